// Round 2
// baseline (1129.365 us; speedup 1.0000x reference)
//
#include <hip/hip_runtime.h>
#include <hip/hip_bf16.h>

typedef _Float16 f16;
typedef f16 f16x2 __attribute__((ext_vector_type(2)));
typedef f16 f16x8 __attribute__((ext_vector_type(8)));
typedef float f32x4 __attribute__((ext_vector_type(4)));

__device__ __forceinline__ float dot2acc(f16x2 a, f16x2 b, float c) {
    return __builtin_amdgcn_fdot2(a, b, c, false);
}
__device__ __forceinline__ float sigmoid_f(float x) {
    return __builtin_amdgcn_rcpf(1.f + __expf(-x));
}
__device__ __forceinline__ float tanh_f(float x) {
    return 1.f - 2.f * __builtin_amdgcn_rcpf(__expf(2.f * x) + 1.f);
}

// ------------------------------------------------- fused weight f32->f16 convert
// Segments (vec4 units): Wp 8192 | Wih_a 49152 | Whh_a 49152 | Wih_b 49152 |
//                        Whh_b 49152 | Wb 16384  => total 221248
__global__ __launch_bounds__(256) void cvt_weights_kernel(
    const float* __restrict__ wp, const float* __restrict__ wia, const float* __restrict__ wha,
    const float* __restrict__ wib, const float* __restrict__ whb, const float* __restrict__ wb,
    f16* __restrict__ o_wp, f16* __restrict__ o_wia, f16* __restrict__ o_wha,
    f16* __restrict__ o_wib, f16* __restrict__ o_whb, f16* __restrict__ o_wb)
{
    int i = blockIdx.x * 256 + threadIdx.x;
    if (i >= 221248) return;
    const float* s; f16* d; int off;
    if      (i < 8192)   { s = wp;  d = o_wp;  off = i; }
    else if (i < 57344)  { s = wia; d = o_wia; off = i - 8192; }
    else if (i < 106496) { s = wha; d = o_wha; off = i - 57344; }
    else if (i < 155648) { s = wib; d = o_wib; off = i - 106496; }
    else if (i < 204800) { s = whb; d = o_whb; off = i - 155648; }
    else                 { s = wb;  d = o_wb;  off = i - 204800; }
    float4 f = ((const float4*)s)[off];
    f16x2 p0; p0.x = (f16)f.x; p0.y = (f16)f.y;
    f16x2 p1; p1.x = (f16)f.z; p1.y = (f16)f.w;
    ((f16x2*)d)[off * 2]     = p0;
    ((f16x2*)d)[off * 2 + 1] = p1;
}

// ---------------------------------------------------------------- MFMA GEMM
// C[M,NOUT] = A[M,KT] @ B[NOUT,KT]^T + bias, tile 128x128, BK=64, 4 waves.
// CVTA: A is fp32, converted to f16 during LDS staging.
// EPI 0/1: out16 = val (f16). EPI 2: out16 = tanh(val) * xp16 (f16 "v").
#define BM 128
#define BN 128
#define BKC 64
#define LPAD 8

template <int KT, int NOUT, int EPI, bool CVTA>
__global__ __launch_bounds__(256) void gemm_kernel(
    const void* __restrict__ Araw, const f16* __restrict__ B,
    const float* __restrict__ bias, f16* __restrict__ out16,
    const f16* __restrict__ xp16)
{
    __shared__ __align__(16) f16 As[BM][BKC + LPAD];
    __shared__ __align__(16) f16 Bs[BN][BKC + LPAD];
    int tid = threadIdx.x;
    int m0 = blockIdx.x * BM, n0 = blockIdx.y * BN;
    int wave = tid >> 6, lane = tid & 63;
    int wm = (wave & 1) * 64, wn = (wave >> 1) * 64;
    int quad = lane >> 4, l16 = lane & 15;

    f32x4 acc[4][4] = {};

    for (int kc = 0; kc < KT / BKC; ++kc) {
        __syncthreads();
#pragma unroll
        for (int i = 0; i < 4; ++i) {
            int idx = i * 256 + tid;
            int row = idx >> 3, c8 = idx & 7;
            if (CVTA) {
                const float* A32 = (const float*)Araw;
                const float* src = A32 + (size_t)(m0 + row) * KT + kc * BKC + c8 * 8;
                float4 fa = *(const float4*)src;
                float4 fb = *(const float4*)(src + 4);
                f16x8 h8;
                h8[0] = (f16)fa.x; h8[1] = (f16)fa.y; h8[2] = (f16)fa.z; h8[3] = (f16)fa.w;
                h8[4] = (f16)fb.x; h8[5] = (f16)fb.y; h8[6] = (f16)fb.z; h8[7] = (f16)fb.w;
                *(f16x8*)&As[row][c8 * 8] = h8;
            } else {
                const f16* A16 = (const f16*)Araw;
                uint4 va = *(const uint4*)(A16 + (size_t)(m0 + row) * KT + kc * BKC + c8 * 8);
                *(uint4*)&As[row][c8 * 8] = va;
            }
            uint4 vb = *(const uint4*)(B + (size_t)(n0 + row) * KT + kc * BKC + c8 * 8);
            *(uint4*)&Bs[row][c8 * 8] = vb;
        }
        __syncthreads();
#pragma unroll
        for (int kk = 0; kk < 2; ++kk) {
            f16x8 af[4], bf[4];
#pragma unroll
            for (int i = 0; i < 4; ++i) {
                af[i] = *(const f16x8*)&As[wm + i * 16 + l16][kk * 32 + quad * 8];
                bf[i] = *(const f16x8*)&Bs[wn + i * 16 + l16][kk * 32 + quad * 8];
            }
#pragma unroll
            for (int mi = 0; mi < 4; ++mi)
#pragma unroll
                for (int ni = 0; ni < 4; ++ni)
                    acc[mi][ni] = __builtin_amdgcn_mfma_f32_16x16x32_f16(af[mi], bf[ni], acc[mi][ni], 0, 0, 0);
        }
    }

#pragma unroll
    for (int ni = 0; ni < 4; ++ni) {
        int col = n0 + wn + ni * 16 + l16;
        float bv = bias[col];
#pragma unroll
        for (int mi = 0; mi < 4; ++mi) {
#pragma unroll
            for (int r = 0; r < 4; ++r) {
                int row = m0 + wm + mi * 16 + quad * 4 + r;
                float val = acc[mi][ni][r] + bv;
                if (EPI == 2) {
                    float tb = tanh_f(val);
                    float xpv = (float)xp16[(size_t)row * NOUT + col];
                    out16[(size_t)row * NOUT + col] = (f16)(tb * xpv);
                } else {
                    out16[(size_t)row * NOUT + col] = (f16)val;
                }
            }
        }
    }
}

// ---------------------------------------------------------------- GRU recurrence
// 256 blocks: blockIdx>>7 selects GRU (0=a,1=b), &127 selects batch element.
// 768 threads: thread j owns Whh row j (128 f16x2 registers).
// h: f16x2 in LDS (double-buffered) for the dot phase; fp32 in registers for update.
// GRU a fuses scores = h . Wa (xa never materialized); GRU b writes h as f16 into d_out.
__global__ __launch_bounds__(768) void rnn_kernel(
    const f16* __restrict__ xwa, const f16* __restrict__ xwb,
    const f16* __restrict__ whha, const f16* __restrict__ whhb,
    const float* __restrict__ bhha, const float* __restrict__ bhhb,
    const float* __restrict__ Wa,
    f16* __restrict__ xb16, float* __restrict__ scores)
{
    int g = blockIdx.x >> 7, b = blockIdx.x & 127;
    int j = threadIdx.x;

    const f16* whh = (g ? whhb : whha) + (size_t)j * 256;
    const float* bhh = g ? bhhb : bhha;
    const f16* xw = (g ? xwb : xwa) + (size_t)b * 512 * 768;

    f16x2 w[128];
#pragma unroll
    for (int k = 0; k < 128; ++k) w[k] = ((const f16x2*)whh)[k];
    float breg = bhh[j];
    float waj = (j < 256) ? Wa[j] : 0.f;

    __shared__ __align__(16) f16x2 h2b[2][128];
    __shared__ float hw[768];
    __shared__ float spart[4];

    if (j < 128) h2b[0][j] = __builtin_bit_cast(f16x2, 0u);
    __syncthreads();

    float hprev = 0.f;
    int cur = 0;
    for (int t = 0; t < 512; ++t) {
        float xr = 0.f, xz = 0.f, xn = 0.f;
        if (j < 256) {
            const f16* xwt = xw + (size_t)t * 768;
            xr = (float)xwt[j];
            xz = (float)xwt[j + 256];
            xn = (float)xwt[j + 512];
        }
        // hW[j] = bhh[j] + dot(h, Whh[j,:])  (uniform-address LDS reads -> broadcast)
        float a0 = breg, a1 = 0.f, a2 = 0.f, a3 = 0.f;
        const uint4* hv = (const uint4*)&h2b[cur][0];
#pragma unroll
        for (int kc = 0; kc < 32; ++kc) {
            uint4 q = hv[kc];
            a0 = dot2acc(__builtin_bit_cast(f16x2, q.x), w[kc * 4 + 0], a0);
            a1 = dot2acc(__builtin_bit_cast(f16x2, q.y), w[kc * 4 + 1], a1);
            a2 = dot2acc(__builtin_bit_cast(f16x2, q.z), w[kc * 4 + 2], a2);
            a3 = dot2acc(__builtin_bit_cast(f16x2, q.w), w[kc * 4 + 3], a3);
        }
        hw[j] = (a0 + a1) + (a2 + a3);
        __syncthreads();  // hW ready

        if (j < 256) {
            float hr = hw[j], hz = hw[j + 256], hn = hw[j + 512];
            float r = sigmoid_f(xr + hr);
            float z = sigmoid_f(xz + hz);
            float n = tanh_f(xn + r * hn);
            float hnew = (1.f - z) * n + z * hprev;
            hprev = hnew;
            float hpair = __shfl_xor(hnew, 1);
            if (!(j & 1)) {
                f16x2 p;
                p.x = (f16)hnew;
                p.y = (f16)hpair;
                h2b[cur ^ 1][j >> 1] = p;
            }
            if (g) {
                xb16[((size_t)(b * 512 + t)) * 256 + j] = (f16)hnew;
            } else {
                float p = hnew * waj;
#pragma unroll
                for (int off = 32; off; off >>= 1) p += __shfl_down(p, off);
                if ((j & 63) == 0) spart[j >> 6] = p;
            }
        }
        __syncthreads();  // h(t+1) + spart ready
        if (!g && j == 0)
            scores[b * 512 + t] = (spart[0] + spart[1]) + (spart[2] + spart[3]);
        cur ^= 1;
    }
}

// ---------------------------------------------------------------- attention
// Prefix softmax == running scan: out[b,t,h] = cumsum(w_s * v[s,h]) / cumsum(w_s),
// w_s = exp(scores[b,s] - max_s scores). One block per batch element. v is f16.
__global__ __launch_bounds__(256) void attn_kernel(
    const float* __restrict__ scores, const f16* __restrict__ v16, float* __restrict__ out)
{
    int b = blockIdx.x, h = threadIdx.x;
    __shared__ float scs[512];
    __shared__ float wle[512];
    __shared__ float red[4];

    scs[h] = scores[b * 512 + h];
    scs[h + 256] = scores[b * 512 + 256 + h];
    __syncthreads();
    float m = fmaxf(scs[h], scs[h + 256]);
#pragma unroll
    for (int off = 32; off; off >>= 1) m = fmaxf(m, __shfl_down(m, off));
    if ((h & 63) == 0) red[h >> 6] = m;
    __syncthreads();
    m = fmaxf(fmaxf(red[0], red[1]), fmaxf(red[2], red[3]));
    wle[h] = __expf(scs[h] - m);
    wle[h + 256] = __expf(scs[h + 256] - m);
    __syncthreads();

    float acc = 0.f, Wc = 0.f;
    const f16* vb = v16 + (size_t)b * 512 * 256 + h;
    float* ob = out + (size_t)b * 512 * 256 + h;
    for (int t8 = 0; t8 < 64; ++t8) {
        float vv[8];
#pragma unroll
        for (int u = 0; u < 8; ++u) vv[u] = (float)vb[(size_t)(t8 * 8 + u) * 256];
#pragma unroll
        for (int u = 0; u < 8; ++u) {
            float wv = wle[t8 * 8 + u];
            Wc += wv;
            acc += wv * vv[u];
            ob[(size_t)(t8 * 8 + u) * 256] = acc * __builtin_amdgcn_rcpf(Wc);
        }
    }
}

// ---------------------------------------------------------------- launch
extern "C" void kernel_launch(void* const* d_in, const int* in_sizes, int n_in,
                              void* d_out, int out_size, void* d_ws, size_t ws_size,
                              hipStream_t stream) {
    const float* x     = (const float*)d_in[0];
    const float* Wp    = (const float*)d_in[1];
    const float* bp    = (const float*)d_in[2];
    const float* Wih_a = (const float*)d_in[3];
    const float* Whh_a = (const float*)d_in[4];
    const float* bih_a = (const float*)d_in[5];
    const float* bhh_a = (const float*)d_in[6];
    const float* Wih_b = (const float*)d_in[7];
    const float* Whh_b = (const float*)d_in[8];
    const float* bih_b = (const float*)d_in[9];
    const float* bhh_b = (const float*)d_in[10];
    const float* Wa    = (const float*)d_in[11];
    // d_in[12] = ba: dropped — softmax is shift-invariant.
    const float* Wb    = (const float*)d_in[13];
    const float* bb    = (const float*)d_in[14];
    float* out = (float*)d_out;

    // Workspace layout (~226 MiB total; keep well under 256 MiB):
    char* ws = (char*)d_ws;
    size_t off = 0;
    auto take = [&](size_t bytes) -> void* {
        void* p = ws + off;
        off += (bytes + 255) & ~(size_t)255;
        return p;
    };
    f16* xp16     = (f16*)take(16777216ull * 2);    // xp [65536,256] f16        32 MiB
    char* xwa_reg = (char*)take(50331648ull * 2);   // xWa f16; later v f16      96 MiB
    f16* xwa16    = (f16*)xwa_reg;
    f16* v16      = (f16*)xwa_reg;                  // alias (xWa dead after rnn)
    f16* xwb16    = (f16*)take(50331648ull * 2);    //                           96 MiB
    float* scores = (float*)take(65536ull * 4);     //                           0.25 MiB
    f16* wp16     = (f16*)take(32768ull * 2);
    f16* wiha16   = (f16*)take(196608ull * 2);
    f16* whha16   = (f16*)take(196608ull * 2);
    f16* wihb16   = (f16*)take(196608ull * 2);
    f16* whhb16   = (f16*)take(196608ull * 2);
    f16* wb16     = (f16*)take(65536ull * 2);
    // xb (GRU-b hidden states, f16, 32 MiB) lives in d_out; overwritten by attn at the end.
    f16* xb16 = (f16*)d_out;
    (void)ws_size; (void)n_in; (void)in_sizes; (void)out_size;

    // 1. all weight conversions in one kernel
    hipLaunchKernelGGL(cvt_weights_kernel, dim3(865), dim3(256), 0, stream,
                       Wp, Wih_a, Whh_a, Wih_b, Whh_b, Wb,
                       wp16, wiha16, whha16, wihb16, whhb16, wb16);
    // 2. xp = x @ Wp^T + bp   (A converted fp32->f16 in staging)
    hipLaunchKernelGGL((gemm_kernel<128, 256, 0, true>), dim3(512, 2), dim3(256), 0, stream,
                       (const void*)x, wp16, bp, xp16, (const f16*)nullptr);
    // 3. xW_a = xp @ Wih_a^T + bih_a ; 4. xW_b likewise
    hipLaunchKernelGGL((gemm_kernel<256, 768, 1, false>), dim3(512, 6), dim3(256), 0, stream,
                       (const void*)xp16, wiha16, bih_a, xwa16, (const f16*)nullptr);
    hipLaunchKernelGGL((gemm_kernel<256, 768, 1, false>), dim3(512, 6), dim3(256), 0, stream,
                       (const void*)xp16, wihb16, bih_b, xwb16, (const f16*)nullptr);
    // 5. both GRUs; fuses scores (GRU a); emits xb f16 into d_out (GRU b)
    hipLaunchKernelGGL(rnn_kernel, dim3(256), dim3(768), 0, stream,
                       xwa16, xwb16, whha16, whhb16, bhh_a, bhh_b, Wa, xb16, scores);
    // 6. beta = tanh(xb @ Wb^T + bb); v = xp * beta  (f16, overwrites xWa region)
    hipLaunchKernelGGL((gemm_kernel<256, 256, 2, false>), dim3(512, 2), dim3(256), 0, stream,
                       (const void*)xb16, wb16, bb, v16, xp16);
    // 7. causal prefix-softmax attention as a running scan (overwrites xb in d_out)
    hipLaunchKernelGGL(attn_kernel, dim3(128), dim3(256), 0, stream, scores, v16, out);
}